// Round 1
// baseline (559.361 us; speedup 1.0000x reference)
//
#include <hip/hip_runtime.h>

typedef __attribute__((ext_vector_type(8))) short short8;
typedef __attribute__((ext_vector_type(4))) float f32x4;

#define B_    32
#define CI_   256
#define H_    56
#define HW_   3136     // 56*56
#define CO_   512
#define OHW_  54
#define PIXB_ 2916     // 54*54
#define NPIX_ 93312    // 32*2916

// ws layout: x_t bf16 [32][56][56][256]  = 51,380,224 B at offset 0
//            w_t bf16 [9][512][256]      =  2,359,296 B at offset 51,380,224
#define XT_BYTES 51380224ull
#define WS_NEED  53739520ull

__device__ __forceinline__ ushort f2bf(float f) {
  unsigned u = __float_as_uint(f);
  unsigned r = (u + 0x7FFFu + ((u >> 16) & 1u)) >> 16;  // RNE
  return (ushort)r;
}

__device__ __forceinline__ void async16(const void* g, void* l) {
  __builtin_amdgcn_global_load_lds(
      (const __attribute__((address_space(1))) unsigned int*)g,
      (__attribute__((address_space(3))) unsigned int*)l, 16, 0, 0);
}

// ---- pre-pass: x [b][ci][h][w] f32 -> x_t [b][h*w][ci] bf16 ------------
__global__ void transpose_x(const float* __restrict__ x, ushort* __restrict__ xt) {
  __shared__ float tile[64][65];                 // +1 pad: conflict-free col reads
  const int b   = blockIdx.z;
  const int hw0 = blockIdx.x * 64;               // 49 tiles (3136 = 49*64)
  const int ci0 = blockIdx.y * 64;               // 4 tiles
  const int t = threadIdx.x;
  const int hwl = t & 63, cil = t >> 6;
  const float* xp = x + ((size_t)b * CI_ + ci0) * HW_ + hw0;
  #pragma unroll
  for (int i = 0; i < 16; ++i) {
    int ci = i * 4 + cil;
    tile[ci][hwl] = xp[(size_t)ci * HW_ + hwl];  // coalesced 256B reads
  }
  __syncthreads();
  const int cil2 = t & 63, hwl2 = t >> 6;
  ushort* op = xt + ((size_t)b * HW_ + hw0) * CI_ + ci0;
  #pragma unroll
  for (int i = 0; i < 16; ++i) {
    int hw = i * 4 + hwl2;
    op[(size_t)hw * CI_ + cil2] = f2bf(tile[cil2][hw]);  // coalesced 128B writes
  }
}

// ---- pre-pass: w [co][ci][kh][kw] f32 -> w_t [khkw][co][ci] bf16 -------
__global__ void repack_w(const float* __restrict__ w, ushort* __restrict__ wt) {
  const int co = blockIdx.x, khkw = blockIdx.y, ci = threadIdx.x;
  float v = w[((size_t)co * CI_ + ci) * 9 + khkw];
  wt[((size_t)khkw * CO_ + co) * CI_ + ci] = f2bf(v);
}

// ---- main: implicit GEMM, 128co x 128pix tile, 16x16x32 bf16 MFMA ------
__global__ __launch_bounds__(256, 3)
void conv_mfma(const ushort* __restrict__ xt, const ushort* __restrict__ wt,
               float* __restrict__ out) {
  __shared__ ushort lds_w[128 * 32];   // A tile: [co_local][ci_local]
  __shared__ ushort lds_x[128 * 32];   // B tile: [pix_local][ci_local]

  const int t    = threadIdx.x;
  const int lane = t & 63;
  const int wv   = t >> 6;
  const int quad = lane >> 4;
  const int l16  = lane & 15;
  const int P0   = blockIdx.x * 128;   // pixel tile (729 of them)
  const int co0  = blockIdx.y * 128;   // co tile (4 of them)

  // staging: thread owns rows row0 and row0+16 in each region, ci chunk ci8
  const int row0 = wv * 32 + (lane >> 2);
  const int ci8  = (lane & 3) * 8;

  const size_t wA0 = (size_t)(co0 + row0) * CI_ + ci8;
  const size_t wA1 = (size_t)(co0 + row0 + 16) * CI_ + ci8;

  int P_a = P0 + row0;
  int b_a = P_a / PIXB_; int rem_a = P_a - b_a * PIXB_;
  int oh_a = rem_a / OHW_; int ow_a = rem_a - oh_a * OHW_;
  const size_t xB0 = ((size_t)b_a * HW_ + oh_a * H_ + ow_a) * CI_ + ci8;
  int P_b = P_a + 16;
  int b_b = P_b / PIXB_; int rem_b = P_b - b_b * PIXB_;
  int oh_b = rem_b / OHW_; int ow_b = rem_b - oh_b * OHW_;
  const size_t xB1 = ((size_t)b_b * HW_ + oh_b * H_ + ow_b) * CI_ + ci8;

  // wave-uniform LDS destinations (HW scatters lane i to base + 16*i)
  char* ldsw_c = (char*)lds_w + wv * 2048;
  char* ldsx_c = (char*)lds_x + wv * 2048;

  f32x4 acc[4][4];
  #pragma unroll
  for (int i = 0; i < 4; ++i)
    #pragma unroll
    for (int j = 0; j < 4; ++j) acc[i][j] = (f32x4){0.f, 0.f, 0.f, 0.f};

  const int wm = (wv & 1) * 64;   // wave's co offset in tile
  const int wn = (wv >> 1) * 64;  // wave's pixel offset in tile

  for (int khkw = 0; khkw < 9; ++khkw) {
    const int kh = khkw / 3, kw = khkw - kh * 3;
    const size_t w_off = (size_t)khkw * CO_ * CI_;
    const size_t x_off = (size_t)(kh * H_ + kw) * CI_;  // shift inside x row: always in-bounds (VALID)
    for (int ci0 = 0; ci0 < CI_; ci0 += 32) {
      async16(wt + wA0 + w_off + ci0, ldsw_c);
      async16(wt + wA1 + w_off + ci0, ldsw_c + 1024);
      async16(xt + xB0 + x_off + ci0, ldsx_c);
      async16(xt + xB1 + x_off + ci0, ldsx_c + 1024);
      __syncthreads();   // drains vmcnt -> LDS tiles ready

      short8 af[4], bfr[4];
      #pragma unroll
      for (int mt = 0; mt < 4; ++mt)
        af[mt] = *(const short8*)&lds_w[(wm + mt * 16 + l16) * 32 + quad * 8];
      #pragma unroll
      for (int nt = 0; nt < 4; ++nt)
        bfr[nt] = *(const short8*)&lds_x[(wn + nt * 16 + l16) * 32 + quad * 8];
      #pragma unroll
      for (int mt = 0; mt < 4; ++mt)
        #pragma unroll
        for (int nt = 0; nt < 4; ++nt)
          acc[mt][nt] = __builtin_amdgcn_mfma_f32_16x16x32_bf16(
              af[mt], bfr[nt], acc[mt][nt], 0, 0, 0);

      __syncthreads();   // all waves done reading before next stage overwrites
    }
  }

  // epilogue: D row = co (quad*4+reg), col = pixel (lane&15)
  #pragma unroll
  for (int nt = 0; nt < 4; ++nt) {
    int P = P0 + wn + nt * 16 + l16;
    int b = P / PIXB_; int rem = P - b * PIXB_;
    size_t obase = (size_t)b * (CO_ * PIXB_) + rem;
    #pragma unroll
    for (int mt = 0; mt < 4; ++mt) {
      int cobase = co0 + wm + mt * 16 + quad * 4;
      #pragma unroll
      for (int r = 0; r < 4; ++r)
        out[obase + (size_t)(cobase + r) * PIXB_] = acc[mt][nt][r];
    }
  }
}

// ---- fallback: direct conv (only if ws too small) ----------------------
__global__ void naive_conv(const float* __restrict__ x, const float* __restrict__ w,
                           float* __restrict__ out) {
  size_t i = (size_t)blockIdx.x * 256 + threadIdx.x;
  if (i >= (size_t)NPIX_ * CO_ / 1) { }
  if (i >= (size_t)47775744ull) return;
  int ow = (int)(i % OHW_); size_t r = i / OHW_;
  int oh = (int)(r % OHW_); r /= OHW_;
  int co = (int)(r % CO_);  int b = (int)(r / CO_);
  const float* xp = x + (size_t)b * CI_ * HW_;
  const float* wp = w + (size_t)co * CI_ * 9;
  float acc = 0.f;
  for (int ci = 0; ci < CI_; ++ci) {
    const float* xr = xp + (size_t)ci * HW_ + oh * H_ + ow;
    const float* wr = wp + ci * 9;
    #pragma unroll
    for (int kh = 0; kh < 3; ++kh)
      #pragma unroll
      for (int kw = 0; kw < 3; ++kw)
        acc += xr[kh * H_ + kw] * wr[kh * 3 + kw];
  }
  out[i] = acc;
}

extern "C" void kernel_launch(void* const* d_in, const int* in_sizes, int n_in,
                              void* d_out, int out_size, void* d_ws, size_t ws_size,
                              hipStream_t stream) {
  const float* x = (const float*)d_in[0];
  const float* w = (const float*)d_in[1];
  float* out = (float*)d_out;

  if (ws_size >= WS_NEED) {
    ushort* xt = (ushort*)d_ws;
    ushort* wt = (ushort*)((char*)d_ws + XT_BYTES);
    transpose_x<<<dim3(49, 4, 32), 256, 0, stream>>>(x, xt);
    repack_w<<<dim3(512, 9), 256, 0, stream>>>(w, wt);
    conv_mfma<<<dim3(729, 4), 256, 0, stream>>>(xt, wt, out);
  } else {
    naive_conv<<<(47775744 + 255) / 256, 256, 0, stream>>>(x, w, out);
  }
}

// Round 3
// 556.374 us; speedup vs baseline: 1.0054x; 1.0054x over previous
//
#include <hip/hip_runtime.h>

typedef __attribute__((ext_vector_type(8))) short short8;
typedef __attribute__((ext_vector_type(4))) float f32x4;

#define B_    32
#define CI_   256
#define H_    56
#define HW_   3136     // 56*56
#define CO_   512
#define OHW_  54
#define PIXB_ 2916     // 54*54
#define NPIX_ 93312    // 32*2916

// ws layout: x_t bf16 [32][56][56][256]  = 51,380,224 B at offset 0
//            w_t bf16 [9][512][256]      =  2,359,296 B at offset 51,380,224
#define XT_BYTES 51380224ull
#define WS_NEED  53739520ull

__device__ __forceinline__ ushort f2bf(float f) {
  unsigned u = __float_as_uint(f);
  unsigned r = (u + 0x7FFFu + ((u >> 16) & 1u)) >> 16;  // RNE
  return (ushort)r;
}

__device__ __forceinline__ void async16(const void* g, void* l) {
  __builtin_amdgcn_global_load_lds(
      (const __attribute__((address_space(1))) unsigned int*)g,
      (__attribute__((address_space(3))) unsigned int*)l, 16, 0, 0);
}

// ---- pre-pass: x [b][ci][h][w] f32 -> x_t [b][h*w][ci] bf16 ------------
// Vectorized: float4 global loads, in-register 4x4 micro-transpose, bf16 LDS
// tile [64 hw][260 ci] (pad 260 => bank-conflict-free b64 writes AND reads),
// ds_read_b64 x2 -> uint4 (16B) coalesced global stores.
#define CIP 260
__global__ __launch_bounds__(256)
void transpose_x(const float* __restrict__ x, ushort* __restrict__ xt) {
  __shared__ ushort tile[64 * CIP];              // 33,280 B
  const int b = blockIdx.y, hw0 = blockIdx.x * 64;
  const int t = threadIdx.x;
  const int j = t & 15, q = t >> 4;              // j: hw4 group, q: ci4 group
  const int hw4 = j * 4;
  const float* xb = x + (size_t)b * CI_ * HW_ + hw0;

  #pragma unroll
  for (int p = 0; p < 4; ++p) {                  // 64 ci per pass
    const int c0 = p * 64 + q * 4;
    float4 v[4];
    #pragma unroll
    for (int r = 0; r < 4; ++r)
      v[r] = *(const float4*)(xb + (size_t)(c0 + r) * HW_ + hw4);
    #pragma unroll
    for (int r2 = 0; r2 < 4; ++r2) {             // r2 = hw offset
      ushort4 o;
      o.x = f2bf(((const float*)&v[0])[r2]);
      o.y = f2bf(((const float*)&v[1])[r2]);
      o.z = f2bf(((const float*)&v[2])[r2]);
      o.w = f2bf(((const float*)&v[3])[r2]);
      *(ushort4*)&tile[(hw4 + r2) * CIP + c0] = o;   // b64, conflict-free
    }
  }
  __syncthreads();

  ushort* ob = xt + ((size_t)b * HW_ + hw0) * CI_;
  #pragma unroll
  for (int p = 0; p < 8; ++p) {
    const int hw  = p * 8 + (t >> 5);
    const int ci8 = (t & 31) * 8;
    const ushort* src = &tile[hw * CIP + ci8];
    uint2 lo = *(const uint2*)src;               // b64 (row offset 520B: 8B-aligned)
    uint2 hi = *(const uint2*)(src + 4);
    uint4 v; v.x = lo.x; v.y = lo.y; v.z = hi.x; v.w = hi.y;
    *(uint4*)(ob + (size_t)hw * CI_ + ci8) = v;  // 16B coalesced
  }
}

// ---- pre-pass: w [co][ci][kh][kw] f32 -> w_t [khkw][co][ci] bf16 -------
// One block per co: coalesced loads into LDS; stride-9 readback is
// conflict-free (gcd(9,32)=1); 512B contiguous writes per khkw.
__global__ __launch_bounds__(256)
void repack_w(const float* __restrict__ w, ushort* __restrict__ wt) {
  __shared__ float buf[2304];
  const int co = blockIdx.x, t = threadIdx.x;
  const float* wp = w + (size_t)co * 2304;
  #pragma unroll
  for (int p = 0; p < 9; ++p) buf[p * 256 + t] = wp[p * 256 + t];
  __syncthreads();
  #pragma unroll
  for (int k = 0; k < 9; ++k)
    wt[(size_t)k * CO_ * CI_ + (size_t)co * CI_ + t] = f2bf(buf[t * 9 + k]);
}

// ---- main: implicit GEMM, 128co x 128pix tile, 16x16x32 bf16 MFMA ------
__global__ __launch_bounds__(256, 3)
void conv_mfma(const ushort* __restrict__ xt, const ushort* __restrict__ wt,
               float* __restrict__ out) {
  __shared__ ushort lds_w[128 * 32];   // A tile: [co_local][ci_local]
  __shared__ ushort lds_x[128 * 32];   // B tile: [pix_local][ci_local]

  const int t    = threadIdx.x;
  const int lane = t & 63;
  const int wv   = t >> 6;
  const int quad = lane >> 4;
  const int l16  = lane & 15;
  // co-fastest swizzle: the 4 co-siblings of one pixel tile run concurrently
  // so 3/4 of x-tile reads hit L2/L3 instead of re-streaming xt 4x.
  const int co0  = (blockIdx.x & 3) * 128;
  const int P0   = (blockIdx.x >> 2) * 128;

  // staging: thread owns rows row0 and row0+16 in each region, ci chunk ci8
  const int row0 = wv * 32 + (lane >> 2);
  const int ci8  = (lane & 3) * 8;

  const size_t wA0 = (size_t)(co0 + row0) * CI_ + ci8;
  const size_t wA1 = (size_t)(co0 + row0 + 16) * CI_ + ci8;

  int P_a = P0 + row0;
  int b_a = P_a / PIXB_; int rem_a = P_a - b_a * PIXB_;
  int oh_a = rem_a / OHW_; int ow_a = rem_a - oh_a * OHW_;
  const size_t xB0 = ((size_t)b_a * HW_ + oh_a * H_ + ow_a) * CI_ + ci8;
  int P_b = P_a + 16;
  int b_b = P_b / PIXB_; int rem_b = P_b - b_b * PIXB_;
  int oh_b = rem_b / OHW_; int ow_b = rem_b - oh_b * OHW_;
  const size_t xB1 = ((size_t)b_b * HW_ + oh_b * H_ + ow_b) * CI_ + ci8;

  // wave-uniform LDS destinations (HW scatters lane i to base + 16*i)
  char* ldsw_c = (char*)lds_w + wv * 2048;
  char* ldsx_c = (char*)lds_x + wv * 2048;

  f32x4 acc[4][4];
  #pragma unroll
  for (int i = 0; i < 4; ++i)
    #pragma unroll
    for (int j = 0; j < 4; ++j) acc[i][j] = (f32x4){0.f, 0.f, 0.f, 0.f};

  const int wm = (wv & 1) * 64;   // wave's co offset in tile
  const int wn = (wv >> 1) * 64;  // wave's pixel offset in tile

  for (int khkw = 0; khkw < 9; ++khkw) {
    const int kh = khkw / 3, kw = khkw - kh * 3;
    const size_t w_off = (size_t)khkw * CO_ * CI_;
    const size_t x_off = (size_t)(kh * H_ + kw) * CI_;  // VALID: always in-bounds
    for (int ci0 = 0; ci0 < CI_; ci0 += 32) {
      async16(wt + wA0 + w_off + ci0, ldsw_c);
      async16(wt + wA1 + w_off + ci0, ldsw_c + 1024);
      async16(xt + xB0 + x_off + ci0, ldsx_c);
      async16(xt + xB1 + x_off + ci0, ldsx_c + 1024);
      __syncthreads();   // drains vmcnt -> LDS tiles ready

      short8 af[4], bfr[4];
      #pragma unroll
      for (int mt = 0; mt < 4; ++mt)
        af[mt] = *(const short8*)&lds_w[(wm + mt * 16 + l16) * 32 + quad * 8];
      #pragma unroll
      for (int nt = 0; nt < 4; ++nt)
        bfr[nt] = *(const short8*)&lds_x[(wn + nt * 16 + l16) * 32 + quad * 8];
      #pragma unroll
      for (int mt = 0; mt < 4; ++mt)
        #pragma unroll
        for (int nt = 0; nt < 4; ++nt)
          acc[mt][nt] = __builtin_amdgcn_mfma_f32_16x16x32_bf16(
              af[mt], bfr[nt], acc[mt][nt], 0, 0, 0);

      __syncthreads();   // all waves done reading before next stage overwrites
    }
  }

  // epilogue: D row = co (quad*4+reg), col = pixel (lane&15)
  #pragma unroll
  for (int nt = 0; nt < 4; ++nt) {
    int P = P0 + wn + nt * 16 + l16;
    int b = P / PIXB_; int rem = P - b * PIXB_;
    size_t obase = (size_t)b * (CO_ * PIXB_) + rem;
    #pragma unroll
    for (int mt = 0; mt < 4; ++mt) {
      int cobase = co0 + wm + mt * 16 + quad * 4;
      #pragma unroll
      for (int r = 0; r < 4; ++r)
        out[obase + (size_t)(cobase + r) * PIXB_] = acc[mt][nt][r];
    }
  }
}

// ---- fallback: direct conv (only if ws too small) ----------------------
__global__ void naive_conv(const float* __restrict__ x, const float* __restrict__ w,
                           float* __restrict__ out) {
  size_t i = (size_t)blockIdx.x * 256 + threadIdx.x;
  if (i >= (size_t)47775744ull) return;
  int ow = (int)(i % OHW_); size_t r = i / OHW_;
  int oh = (int)(r % OHW_); r /= OHW_;
  int co = (int)(r % CO_);  int b = (int)(r / CO_);
  const float* xp = x + (size_t)b * CI_ * HW_;
  const float* wp = w + (size_t)co * CI_ * 9;
  float acc = 0.f;
  for (int ci = 0; ci < CI_; ++ci) {
    const float* xr = xp + (size_t)ci * HW_ + oh * H_ + ow;
    const float* wr = wp + ci * 9;
    #pragma unroll
    for (int kh = 0; kh < 3; ++kh)
      #pragma unroll
      for (int kw = 0; kw < 3; ++kw)
        acc += xr[kh * H_ + kw] * wr[kh * 3 + kw];
  }
  out[i] = acc;
}

extern "C" void kernel_launch(void* const* d_in, const int* in_sizes, int n_in,
                              void* d_out, int out_size, void* d_ws, size_t ws_size,
                              hipStream_t stream) {
  const float* x = (const float*)d_in[0];
  const float* w = (const float*)d_in[1];
  float* out = (float*)d_out;

  if (ws_size >= WS_NEED) {
    ushort* xt = (ushort*)d_ws;
    ushort* wt = (ushort*)((char*)d_ws + XT_BYTES);
    transpose_x<<<dim3(49, 32), 256, 0, stream>>>(x, xt);
    repack_w<<<dim3(512), 256, 0, stream>>>(w, wt);
    conv_mfma<<<dim3(2916), 256, 0, stream>>>(xt, wt, out);
  } else {
    naive_conv<<<(47775744 + 255) / 256, 256, 0, stream>>>(x, w, out);
  }
}